// Round 8
// baseline (228.810 us; speedup 1.0000x reference)
//
#include <hip/hip_runtime.h>

#define S_LEN 2048
#define NB    2
#define EMB   1024
#define NH    16
#define HD    64

typedef __bf16 bf16_t;
typedef bf16_t bf16x8 __attribute__((ext_vector_type(8)));
typedef bf16_t bf16x4v __attribute__((ext_vector_type(4)));
typedef float  f32x4  __attribute__((ext_vector_type(4)));
typedef float  f32x16 __attribute__((ext_vector_type(16)));

#define L2E 1.44269504f   // log2(e)

// async global->LDS, 16B per lane; LDS dest = wave-uniform base + lane*16
__device__ __forceinline__ void g2l16(const void* g, void* l) {
    auto gp = reinterpret_cast<const unsigned int __attribute__((address_space(1)))*>(
        reinterpret_cast<uintptr_t>(g));
    auto lp = reinterpret_cast<unsigned int __attribute__((address_space(3)))*>(
        reinterpret_cast<uintptr_t>(l));
    __builtin_amdgcn_global_load_lds(gp, lp, 16, 0, 0);
}

// pack two f32 -> one u32 of 2 bf16 (h[0] = a = low address on store)
__device__ __forceinline__ unsigned int pk2(float a, float b) {
    union { unsigned int u; bf16_t h[2]; } r;
    r.h[0] = (bf16_t)a; r.h[1] = (bf16_t)b;
    return r.u;
}

// ---------------------------------------------------------------------------
// Fused fp32 -> bf16 cast of x, w_tor, in_proj_w, out_w (float4 granularity).
// ---------------------------------------------------------------------------
__global__ __launch_bounds__(256) void cast4_f32_bf16(
    const float* __restrict__ s0, bf16_t* __restrict__ d0,
    const float* __restrict__ s1, bf16_t* __restrict__ d1,
    const float* __restrict__ s2, bf16_t* __restrict__ d2,
    const float* __restrict__ s3, bf16_t* __restrict__ d3)
{
    long i = (long)blockIdx.x * 256 + threadIdx.x;
    const float* s; bf16_t* d; long off;
    if (i < 1048576)      { s = s0; d = d0; off = i; }
    else if (i < 1310720) { s = s1; d = d1; off = i - 1048576; }
    else if (i < 2097152) { s = s2; d = d2; off = i - 1310720; }
    else                  { s = s3; d = d3; off = i - 2097152; }
    float4 v = ((const float4*)s)[off];
    bf16x4v o;
    o[0] = (bf16_t)v.x; o[1] = (bf16_t)v.y; o[2] = (bf16_t)v.z; o[3] = (bf16_t)v.w;
    *(bf16x4v*)(d + off * 4) = o;
}

// ---------------------------------------------------------------------------
// bf16 MFMA GEMM, double-buffered prefetch K-loop (1 barrier/iter).
// C(M,N) = A(M,K) @ W(N,K)^T + bias(N). TM=128, TN in {64,128}, BK=32.
// MODE: 0 = fp32 out, 1 = bf16 out, 2 = qkv head-layout epilogue:
//   Q pre-scaled by 0.125*log2e; K natural [b,h,s,d]; V transposed [b,h,d,s]
//   with KEY-SLOT PERMUTATION (swap bits 2<->3 of s): makes the attn PV
//   A-fragment equal an in-lane repack of the QK^T output (P stays in regs).
// R6 lesson pinned: 256^2-tile GEMM2 = 192 blocks on 256 CUs (25% idle) +
// 1 block/CU -> regressed 10us. 128^2 (768 blocks, 2/CU) is the optimum here.
// ---------------------------------------------------------------------------
template<int TN, int MODE>
__global__ __launch_bounds__(256) void gemm_bt_bf16(
    const bf16_t* __restrict__ A, const bf16_t* __restrict__ W,
    const float* __restrict__ bias, void* __restrict__ Cout,
    bf16_t* __restrict__ Qp, bf16_t* __restrict__ Kp, bf16_t* __restrict__ Vtp,
    int M, int N, int K)
{
    constexpr int MB = (TN == 128) ? 4 : 2;
    __shared__ __align__(16) bf16_t As[2][128 * 32];
    __shared__ __align__(16) bf16_t Bs[2][TN * 32];

    const int tid  = threadIdx.x;
    const int lane = tid & 63;
    const int w    = tid >> 6;
    const int lm   = lane & 15;
    const int lq   = lane >> 4;
    const long m0  = (long)blockIdx.y * 128;
    const long n0  = (long)blockIdx.x * TN;
    const int wm0  = (TN == 128) ? (w >> 1) * 64 : w * 32;
    const int wn0  = (TN == 128) ? (w & 1) * 64 : 0;

    f32x4 acc[MB][4];
#pragma unroll
    for (int i = 0; i < MB; ++i)
#pragma unroll
        for (int j = 0; j < 4; ++j) acc[i][j] = (f32x4){0.f, 0.f, 0.f, 0.f};

    auto stage = [&](int k0, int buf) {
        bf16_t* asb = &As[buf][0];
        bf16_t* bsb = &Bs[buf][0];
#pragma unroll
        for (int j = 0; j < 2; ++j) {
            int a   = (w * 2 + j) * 64 + lane;
            int row = a >> 2;
            int c   = (a & 3) ^ ((row >> 1) & 3);
            g2l16(A + (m0 + row) * K + k0 + c * 8, asb + (w * 2 + j) * 512);
        }
#pragma unroll
        for (int j = 0; j < TN / 64; ++j) {
            int a   = (w * (TN / 64) + j) * 64 + lane;
            int row = a >> 2;
            int c   = (a & 3) ^ ((row >> 1) & 3);
            g2l16(W + (n0 + row) * K + k0 + c * 8, bsb + (w * (TN / 64) + j) * 512);
        }
    };

    stage(0, 0);
    for (int k0 = 0; k0 < K; k0 += 32) {
        const int cur = (k0 >> 5) & 1;
        asm volatile("s_waitcnt vmcnt(0)" ::: "memory");
        __syncthreads();
        if (k0 + 32 < K) stage(k0 + 32, cur ^ 1);

        bf16x8 af[MB], bfr[4];
#pragma unroll
        for (int mb = 0; mb < MB; ++mb) {
            int r = wm0 + mb * 16 + lm;
            af[mb] = *(const bf16x8*)&As[cur][r * 32 + ((lq ^ ((r >> 1) & 3)) << 3)];
        }
#pragma unroll
        for (int nb = 0; nb < 4; ++nb) {
            int r = wn0 + nb * 16 + lm;
            bfr[nb] = *(const bf16x8*)&Bs[cur][r * 32 + ((lq ^ ((r >> 1) & 3)) << 3)];
        }
#pragma unroll
        for (int mb = 0; mb < MB; ++mb)
#pragma unroll
            for (int nb = 0; nb < 4; ++nb)
                acc[mb][nb] = __builtin_amdgcn_mfma_f32_16x16x32_bf16(
                    af[mb], bfr[nb], acc[mb][nb], 0, 0, 0);
    }

    // ---- epilogue ----
    float b4[4];
#pragma unroll
    for (int nb = 0; nb < 4; ++nb) b4[nb] = bias[n0 + wn0 + nb * 16 + lm];

    if (MODE == 2) {
#pragma unroll
        for (int mb = 0; mb < MB; ++mb) {
            const long mbase = m0 + wm0 + mb * 16 + lq * 4;   // even
#pragma unroll
            for (int nb = 0; nb < 4; ++nb) {
                int n    = (int)n0 + wn0 + nb * 16 + lm;
                int sec  = n >> 10;
                int nloc = n & 1023;
                int h    = nloc >> 6;
                int d    = nloc & 63;
                if (sec == 2) {
                    // paired Vt store at PERMUTED slot: swap bits 2<->3 of s
                    int s0 = (int)(mbase >> 1);
                    int sp = (s0 & ~12) | ((s0 & 4) << 1) | ((s0 & 8) >> 1);
#pragma unroll
                    for (int rp = 0; rp < 2; ++rp) {
                        int bh = rp * 16 + h;
                        unsigned int pkv = pk2(acc[mb][nb][rp]     + b4[nb],
                                               acc[mb][nb][rp + 2] + b4[nb]);
                        *(unsigned int*)&Vtp[((size_t)(bh * 64 + d)) * S_LEN + sp] = pkv;
                    }
                } else {
#pragma unroll
                    for (int r = 0; r < 4; ++r) {
                        long m  = mbase + r;
                        int  s  = (int)(m >> 1), b = (int)(m & 1);
                        int  bh = b * 16 + h;
                        float v = acc[mb][nb][r] + b4[nb];
                        if (sec == 0) {
                            Qp[((size_t)(bh * S_LEN + s)) * 64 + d] =
                                (bf16_t)(v * (0.125f * L2E));
                        } else {
                            Kp[((size_t)(bh * S_LEN + s)) * 64 + d] = (bf16_t)v;
                        }
                    }
                }
            }
        }
    } else {
#pragma unroll
        for (int mb = 0; mb < MB; ++mb) {
#pragma unroll
            for (int r = 0; r < 4; ++r) {
                long m = m0 + wm0 + mb * 16 + lq * 4 + r;
#pragma unroll
                for (int nb = 0; nb < 4; ++nb) {
                    int n   = (int)n0 + wn0 + nb * 16 + lm;
                    float v = acc[mb][nb][r] + b4[nb];
                    if (MODE == 0) ((float*)Cout)[m * N + n] = v;
                    else           ((bf16_t*)Cout)[m * N + n] = (bf16_t)v;
                }
            }
        }
    }
}

// ---------------------------------------------------------------------------
// MFMA flash attention — R3 skeleton (256 thr / 4 waves / 32 iters / 2
// blocks per CU, XCD bh swizzle, setprio) + R7 in-register P (V key rows
// bit-2/3-swapped by GEMM2) + R8: V BYPASSES LDS.
//   R7 accounting: LDS pipe ~33% of wall (80KB/block-iter), VMEM idle, K/V
//   L2-resident. V's LDS reuse was only 4x and its fragment is a contiguous
//   16B global read: lane (l5,hi) loads Vt[d=dh*32+l5][kt*64+16ks+8hi..+7]
//   direct to regs, issued right after the barrier (QK^T+exp2 ~300cyc covers
//   L1/L2 latency). Removes V staging writes + V LDS reads (= half of all
//   LDS traffic) and 2 g2l16/wave-iter; frees 16 KB LDS.
//   K stays LDS-staged (8x reuse, anchors the dbuf/barrier structure):
//   coalesced staging + XOR slot(row,c)=row*8+(c^(row&7)).
// Pinned: R1 permlane-P slower; R2 key-split slower; R4 1 wave/SIMD much
// slower; 2 blocks/CU minimum for pipe overlap.
// ---------------------------------------------------------------------------
__global__ __launch_bounds__(256, 2) void attn_mfma(
    const bf16_t* __restrict__ Qb, const bf16_t* __restrict__ Kb,
    const bf16_t* __restrict__ Vtb, bf16_t* __restrict__ O)
{
    __shared__ __align__(16) bf16_t Ks[2][8 * 512];    // 16 KB, swizzled rows
    __shared__ __align__(16) float  Lw4[4][32];        // per-wave row sums

    const int tid  = threadIdx.x;
    const int lane = tid & 63;
    const int w    = tid >> 6;
    const int bid  = blockIdx.x;
    // XCD swizzle: XCD x gets blocks {x, x+8, ...} = 4 consecutive bh
    const int bh   = ((bid & 7) << 2) | (bid >> 7);
    const int qt   = (bid >> 3) & 15;
    const int l5   = lane & 31;
    const int hi   = lane >> 5;

    // staging lane geometry: row-within-8-group + inverse-swizzled chunk
    const int rsub = lane >> 3;                  // 0..7
    const int csw  = (lane & 7) ^ rsub;          // chunk this lane fetches
    // K fragment-read swizzled chunk offsets (elements), per-lane constant
    int cc[4];
#pragma unroll
    for (int i = 0; i < 4; ++i) cc[i] = ((2 * i + hi) ^ (l5 & 7)) * 8;

    // Q B-frags (B[n=q][k=d]), q = qt*128 + w*32 + l5, held in regs
    const bf16_t* qrow = Qb + ((size_t)bh * S_LEN + qt * 128 + w * 32 + l5) * 64 + hi * 8;
    bf16x8 qf[4];
#pragma unroll
    for (int ds = 0; ds < 4; ++ds) qf[ds] = *(const bf16x8*)(qrow + ds * 16);

    // V direct-load base: lane (l5,hi) reads rows d = dh*32+l5
    const bf16_t* vb0 = Vtb + (size_t)bh * 64 * S_LEN + (size_t)l5 * S_LEN + hi * 8;

    f32x16 oacc[2];
#pragma unroll
    for (int dh = 0; dh < 2; ++dh)
#pragma unroll
        for (int i = 0; i < 16; ++i) oacc[dh][i] = 0.f;
    float plsum = 0.f;

    // coalesced K staging: instr i covers rows 8i..8i+7 -> bytes [1024i, +1024)
    auto stageK = [&](int kt, int buf) {
        bf16_t* ksb = &Ks[buf][0];
        const bf16_t* kg = Kb + ((size_t)bh * S_LEN + kt * 64) * 64;
#pragma unroll
        for (int j = 0; j < 2; ++j) {
            int i = w * 2 + j;
            g2l16(kg + (size_t)(i * 8 + rsub) * 64 + csw * 8, ksb + i * 512);
        }
    };

    stageK(0, 0);
    for (int kt = 0; kt < 32; ++kt) {
        const int cur = kt & 1;
        asm volatile("s_waitcnt vmcnt(0)" ::: "memory");
        __syncthreads();
        if (kt < 31) stageK(kt + 1, cur ^ 1);

        // ---- V fragments: direct global->reg, issued early for latency cover
        bf16x8 vf[2][4];
#pragma unroll
        for (int dh = 0; dh < 2; ++dh)
#pragma unroll
            for (int ks = 0; ks < 4; ++ks)
                vf[dh][ks] = *(const bf16x8*)(vb0 + (size_t)dh * 32 * S_LEN
                                                  + kt * 64 + ks * 16);

        // ---- S^T = K·Q^T per key half (log2 domain) ----
        f32x16 sacc[2];
        __builtin_amdgcn_s_setprio(1);
#pragma unroll
        for (int kh = 0; kh < 2; ++kh) {
#pragma unroll
            for (int i = 0; i < 16; ++i) sacc[kh][i] = 0.f;
#pragma unroll
            for (int ds = 0; ds < 4; ++ds) {
                bf16x8 kf = *(const bf16x8*)&Ks[cur][(kh * 32 + l5) * 64 + cc[ds]];
                sacc[kh] = __builtin_amdgcn_mfma_f32_32x32x16_bf16(kf, qf[ds], sacc[kh], 0, 0, 0);
            }
        }
        __builtin_amdgcn_s_setprio(0);

        // ---- toroidal bias: only near-diagonal K-tiles ----
        int ktd = (kt - 2 * qt) & 31;
        if (ktd <= 2 || ktd == 31) {
            int q = qt * 128 + w * 32 + l5;
#pragma unroll
            for (int kh = 0; kh < 2; ++kh)
#pragma unroll
                for (int r = 0; r < 16; ++r) {
                    int key  = kt * 64 + kh * 32 + (r & 3) + 8 * (r >> 2) + 4 * hi;
                    int diff = (key - q) & (S_LEN - 1);
                    if (diff <= 1 || diff == S_LEN - 1) sacc[kh][r] += L2E;
                }
        }

        // ---- p = 2^S, all in registers ----
        float pv[2][16];
#pragma unroll
        for (int kh = 0; kh < 2; ++kh)
#pragma unroll
            for (int i = 0; i < 16; ++i) {
                pv[kh][i] = __builtin_amdgcn_exp2f(sacc[kh][i]);
                plsum += pv[kh][i];
            }

        // ---- PV A-frags: pure in-lane repack (V rows are bit-2/3-swapped) ----
        bf16x8 pf[4];
#pragma unroll
        for (int ks = 0; ks < 4; ++ks) {
            const int kh = ks >> 1, m = ks & 1;
#pragma unroll
            for (int e = 0; e < 8; ++e)
                pf[ks][e] = (bf16_t)pv[kh][(e & 3) + 8 * m + 4 * (e >> 2)];
        }

        // ---- PV: O[q][d] += P·V (V in regs) ----
        __builtin_amdgcn_s_setprio(1);
#pragma unroll
        for (int dh = 0; dh < 2; ++dh) {
#pragma unroll
            for (int ks = 0; ks < 4; ++ks) {
                oacc[dh] = __builtin_amdgcn_mfma_f32_32x32x16_bf16(
                    pf[ks], vf[dh][ks], oacc[dh], 0, 0, 0);
            }
        }
        __builtin_amdgcn_s_setprio(0);
    }

    // ---- l: lane + lane^32 hold the two key-halves of row q=l5 ----
    plsum += __shfl_xor(plsum, 32, 64);
    if (hi == 0) Lw4[w][l5] = plsum;

    float inv16[16];
#pragma unroll
    for (int g = 0; g < 4; ++g) {
        f32x4 lv = *(const f32x4*)&Lw4[w][8 * g + 4 * hi];
#pragma unroll
        for (int e = 0; e < 4; ++e) inv16[g * 4 + e] = 1.0f / lv[e];
    }

    const int b = bh >> 4, h = bh & 15;
#pragma unroll
    for (int dh = 0; dh < 2; ++dh)
#pragma unroll
        for (int r = 0; r < 16; ++r) {
            int qrel = (r & 3) + 8 * (r >> 2) + 4 * hi;
            int s = qt * 128 + w * 32 + qrel;
            O[((size_t)(s * NB + b)) * EMB + h * 64 + dh * 32 + l5] =
                (bf16_t)(oacc[dh][r] * inv16[r]);
        }
}

// ---------------------------------------------------------------------------
// Workspace map (42 MB):
//   [ 0, 8) xb -> reused as Qb | [ 8,10) wtorb | [10,16) ipwb | [16,18) outwb
//   [18,26) xtb -> reused as Ob | [26,34) Kb | [34,42) Vtb (permuted cols)
// ---------------------------------------------------------------------------
extern "C" void kernel_launch(void* const* d_in, const int* in_sizes, int n_in,
                              void* d_out, int out_size, void* d_ws, size_t ws_size,
                              hipStream_t stream)
{
    const float* x         = (const float*)d_in[0];
    const float* w_tor     = (const float*)d_in[1];
    const float* b_tor     = (const float*)d_in[2];
    const float* in_proj_w = (const float*)d_in[3];
    const float* in_proj_b = (const float*)d_in[4];
    const float* out_w     = (const float*)d_in[5];
    const float* out_b     = (const float*)d_in[6];
    float* out = (float*)d_out;

    const int M = S_LEN * NB;   // 4096

    char* base = (char*)d_ws;
    bf16_t* xb    = (bf16_t*)(base);
    bf16_t* wtorb = (bf16_t*)(base + ( 8ull << 20));
    bf16_t* ipwb  = (bf16_t*)(base + (10ull << 20));
    bf16_t* outwb = (bf16_t*)(base + (16ull << 20));
    bf16_t* xtb   = (bf16_t*)(base + (18ull << 20));
    bf16_t* Kb    = (bf16_t*)(base + (26ull << 20));
    bf16_t* Vtb   = (bf16_t*)(base + (34ull << 20));
    bf16_t* Qb    = xb;    // alias: xb dead once GEMM1 has run
    bf16_t* Ob    = xtb;   // alias: xtb dead once GEMM2 has run

    cast4_f32_bf16<<<dim3(9216), 256, 0, stream>>>(
        x, xb, w_tor, wtorb, in_proj_w, ipwb, out_w, outwb);

    gemm_bt_bf16<64, 1><<<dim3(EMB / 64, M / 128), 256, 0, stream>>>(
        xb, wtorb, b_tor, xtb, nullptr, nullptr, nullptr, M, EMB, EMB);

    gemm_bt_bf16<128, 2><<<dim3(3 * EMB / 128, M / 128), 256, 0, stream>>>(
        xtb, ipwb, in_proj_b, nullptr, Qb, Kb, Vtb, M, 3 * EMB, EMB);

    attn_mfma<<<dim3(32 * 16), 256, 0, stream>>>(Qb, Kb, Vtb, Ob);

    gemm_bt_bf16<64, 0><<<dim3(EMB / 64, M / 128), 256, 0, stream>>>(
        Ob, outwb, out_b, out, nullptr, nullptr, nullptr, M, EMB, EMB);
}

// Round 10
// 208.805 us; speedup vs baseline: 1.0958x; 1.0958x over previous
//
#include <hip/hip_runtime.h>

#define S_LEN 2048
#define NB    2
#define EMB   1024
#define NH    16
#define HD    64

typedef __bf16 bf16_t;
typedef bf16_t bf16x8 __attribute__((ext_vector_type(8)));
typedef bf16_t bf16x4v __attribute__((ext_vector_type(4)));
typedef float  f32x4  __attribute__((ext_vector_type(4)));
typedef float  f32x16 __attribute__((ext_vector_type(16)));

#define L2E 1.44269504f   // log2(e)

// async global->LDS, 16B per lane; LDS dest = wave-uniform base + lane*16
__device__ __forceinline__ void g2l16(const void* g, void* l) {
    auto gp = reinterpret_cast<const unsigned int __attribute__((address_space(1)))*>(
        reinterpret_cast<uintptr_t>(g));
    auto lp = reinterpret_cast<unsigned int __attribute__((address_space(3)))*>(
        reinterpret_cast<uintptr_t>(l));
    __builtin_amdgcn_global_load_lds(gp, lp, 16, 0, 0);
}

// pack two f32 -> one u32 of 2 bf16 (h[0] = a = low address on store)
__device__ __forceinline__ unsigned int pk2(float a, float b) {
    union { unsigned int u; bf16_t h[2]; } r;
    r.h[0] = (bf16_t)a; r.h[1] = (bf16_t)b;
    return r.u;
}

// ---------------------------------------------------------------------------
// Fused fp32 -> bf16 cast of x, w_tor, in_proj_w, out_w (float4 granularity).
// ---------------------------------------------------------------------------
__global__ __launch_bounds__(256) void cast4_f32_bf16(
    const float* __restrict__ s0, bf16_t* __restrict__ d0,
    const float* __restrict__ s1, bf16_t* __restrict__ d1,
    const float* __restrict__ s2, bf16_t* __restrict__ d2,
    const float* __restrict__ s3, bf16_t* __restrict__ d3)
{
    long i = (long)blockIdx.x * 256 + threadIdx.x;
    const float* s; bf16_t* d; long off;
    if (i < 1048576)      { s = s0; d = d0; off = i; }
    else if (i < 1310720) { s = s1; d = d1; off = i - 1048576; }
    else if (i < 2097152) { s = s2; d = d2; off = i - 1310720; }
    else                  { s = s3; d = d3; off = i - 2097152; }
    float4 v = ((const float4*)s)[off];
    bf16x4v o;
    o[0] = (bf16_t)v.x; o[1] = (bf16_t)v.y; o[2] = (bf16_t)v.z; o[3] = (bf16_t)v.w;
    *(bf16x4v*)(d + off * 4) = o;
}

// ---------------------------------------------------------------------------
// bf16 MFMA GEMM, double-buffered prefetch K-loop (1 barrier/iter).
// C(M,N) = A(M,K) @ W(N,K)^T + bias(N). TM=128, TN in {64,128}, BK=32.
// MODE: 0 = fp32 out, 1 = bf16 out, 2 = qkv head-layout epilogue:
//   Q pre-scaled by 0.125*log2e; K natural [b,h,s,d]; V transposed [b,h,d,s]
//   with KEY-SLOT PERMUTATION (swap bits 2<->3 of s): makes the attn PV
//   A-fragment equal an in-lane repack of the QK^T output (P stays in regs).
// R9: bijective 2D-rect XCD swizzle (T1). 1D grid; XCD x owns the tile
//   rectangle m-rows [(x>>1)*MT/4, +MT/4) x n-cols [(x&1)*NT/2, +NT/2):
//   A-panel (2MB) + W-panel (<=3MB) per XCD are L2-resident instead of every
//   XCD re-fetching every panel (default x-major dispatch re-fetched A ~8x).
// Pinned: R6 256^2-tile GEMM2 (192 blocks, 1/CU) regressed 10us — 128^2 it is.
// ---------------------------------------------------------------------------
template<int TN, int MODE, int MT, int NT>
__global__ __launch_bounds__(256) void gemm_bt_bf16(
    const bf16_t* __restrict__ A, const bf16_t* __restrict__ W,
    const float* __restrict__ bias, void* __restrict__ Cout,
    bf16_t* __restrict__ Qp, bf16_t* __restrict__ Kp, bf16_t* __restrict__ Vtp,
    int M, int N, int K)
{
    constexpr int MB = (TN == 128) ? 4 : 2;
    __shared__ __align__(16) bf16_t As[2][128 * 32];
    __shared__ __align__(16) bf16_t Bs[2][TN * 32];

    const int tid  = threadIdx.x;
    const int lane = tid & 63;
    const int w    = tid >> 6;
    const int lm   = lane & 15;
    const int lq   = lane >> 4;

    // 2D-rect XCD swizzle: 4 m-rects x 2 n-rects = 8 XCDs
    constexpr int MR = MT / 4;
    constexpr int NR = NT / 2;
    const int bid  = blockIdx.x;
    const int xcd  = bid & 7;
    const int idx  = bid >> 3;                 // [0, MR*NR)
    const long m0  = (long)((xcd >> 1) * MR + idx / NR) * 128;
    const long n0  = (long)((xcd & 1) * NR + idx % NR) * TN;

    const int wm0  = (TN == 128) ? (w >> 1) * 64 : w * 32;
    const int wn0  = (TN == 128) ? (w & 1) * 64 : 0;

    f32x4 acc[MB][4];
#pragma unroll
    for (int i = 0; i < MB; ++i)
#pragma unroll
        for (int j = 0; j < 4; ++j) acc[i][j] = (f32x4){0.f, 0.f, 0.f, 0.f};

    auto stage = [&](int k0, int buf) {
        bf16_t* asb = &As[buf][0];
        bf16_t* bsb = &Bs[buf][0];
#pragma unroll
        for (int j = 0; j < 2; ++j) {
            int a   = (w * 2 + j) * 64 + lane;
            int row = a >> 2;
            int c   = (a & 3) ^ ((row >> 1) & 3);
            g2l16(A + (m0 + row) * K + k0 + c * 8, asb + (w * 2 + j) * 512);
        }
#pragma unroll
        for (int j = 0; j < TN / 64; ++j) {
            int a   = (w * (TN / 64) + j) * 64 + lane;
            int row = a >> 2;
            int c   = (a & 3) ^ ((row >> 1) & 3);
            g2l16(W + (n0 + row) * K + k0 + c * 8, bsb + (w * (TN / 64) + j) * 512);
        }
    };

    stage(0, 0);
    for (int k0 = 0; k0 < K; k0 += 32) {
        const int cur = (k0 >> 5) & 1;
        asm volatile("s_waitcnt vmcnt(0)" ::: "memory");
        __syncthreads();
        if (k0 + 32 < K) stage(k0 + 32, cur ^ 1);

        bf16x8 af[MB], bfr[4];
#pragma unroll
        for (int mb = 0; mb < MB; ++mb) {
            int r = wm0 + mb * 16 + lm;
            af[mb] = *(const bf16x8*)&As[cur][r * 32 + ((lq ^ ((r >> 1) & 3)) << 3)];
        }
#pragma unroll
        for (int nb = 0; nb < 4; ++nb) {
            int r = wn0 + nb * 16 + lm;
            bfr[nb] = *(const bf16x8*)&Bs[cur][r * 32 + ((lq ^ ((r >> 1) & 3)) << 3)];
        }
#pragma unroll
        for (int mb = 0; mb < MB; ++mb)
#pragma unroll
            for (int nb = 0; nb < 4; ++nb)
                acc[mb][nb] = __builtin_amdgcn_mfma_f32_16x16x32_bf16(
                    af[mb], bfr[nb], acc[mb][nb], 0, 0, 0);
    }

    // ---- epilogue ----
    float b4[4];
#pragma unroll
    for (int nb = 0; nb < 4; ++nb) b4[nb] = bias[n0 + wn0 + nb * 16 + lm];

    if (MODE == 2) {
#pragma unroll
        for (int mb = 0; mb < MB; ++mb) {
            const long mbase = m0 + wm0 + mb * 16 + lq * 4;   // even
#pragma unroll
            for (int nb = 0; nb < 4; ++nb) {
                int n    = (int)n0 + wn0 + nb * 16 + lm;
                int sec  = n >> 10;
                int nloc = n & 1023;
                int h    = nloc >> 6;
                int d    = nloc & 63;
                if (sec == 2) {
                    // paired Vt store at PERMUTED slot: swap bits 2<->3 of s
                    int s0 = (int)(mbase >> 1);
                    int sp = (s0 & ~12) | ((s0 & 4) << 1) | ((s0 & 8) >> 1);
#pragma unroll
                    for (int rp = 0; rp < 2; ++rp) {
                        int bh = rp * 16 + h;
                        unsigned int pkv = pk2(acc[mb][nb][rp]     + b4[nb],
                                               acc[mb][nb][rp + 2] + b4[nb]);
                        *(unsigned int*)&Vtp[((size_t)(bh * 64 + d)) * S_LEN + sp] = pkv;
                    }
                } else {
#pragma unroll
                    for (int r = 0; r < 4; ++r) {
                        long m  = mbase + r;
                        int  s  = (int)(m >> 1), b = (int)(m & 1);
                        int  bh = b * 16 + h;
                        float v = acc[mb][nb][r] + b4[nb];
                        if (sec == 0) {
                            Qp[((size_t)(bh * S_LEN + s)) * 64 + d] =
                                (bf16_t)(v * (0.125f * L2E));
                        } else {
                            Kp[((size_t)(bh * S_LEN + s)) * 64 + d] = (bf16_t)v;
                        }
                    }
                }
            }
        }
    } else {
#pragma unroll
        for (int mb = 0; mb < MB; ++mb) {
#pragma unroll
            for (int r = 0; r < 4; ++r) {
                long m = m0 + wm0 + mb * 16 + lq * 4 + r;
#pragma unroll
                for (int nb = 0; nb < 4; ++nb) {
                    int n   = (int)n0 + wn0 + nb * 16 + lm;
                    float v = acc[mb][nb][r] + b4[nb];
                    if (MODE == 0) ((float*)Cout)[m * N + n] = v;
                    else           ((bf16_t*)Cout)[m * N + n] = (bf16_t)v;
                }
            }
        }
    }
}

// ---------------------------------------------------------------------------
// MFMA flash attention — R7 configuration restored VERBATIM (measured 50.4us,
// best of R0..R8): R3 skeleton (256 thr / 4 waves / 32 iters / 2 blocks/CU,
// coalesced staging + XOR slot(row,c)=row*8+(c^(row&7)) K/V layout, XCD bh
// swizzle, setprio) + in-register P via V key-row bit-2/3 swap.
// Pinned lessons: R1 permlane-P slower (serial VALU); R2 key-split slower;
// R4 64q/wave (1 wave/SIMD) much slower; R8 V-bypass-LDS much slower (direct
// V reg loads = 32 lines/instr uncoalesced gather); 2 blocks/CU minimum.
// ---------------------------------------------------------------------------
__global__ __launch_bounds__(256, 2) void attn_mfma(
    const bf16_t* __restrict__ Qb, const bf16_t* __restrict__ Kb,
    const bf16_t* __restrict__ Vtb, bf16_t* __restrict__ O)
{
    __shared__ __align__(16) bf16_t Ks[2][8 * 512];    // 16 KB, swizzled rows
    __shared__ __align__(16) bf16_t Vts[2][8 * 512];   // 16 KB, swizzled rows
    __shared__ __align__(16) float  Lw4[4][32];        // per-wave row sums

    const int tid  = threadIdx.x;
    const int lane = tid & 63;
    const int w    = tid >> 6;
    const int bid  = blockIdx.x;
    // XCD swizzle: XCD x gets blocks {x, x+8, ...} = 4 consecutive bh
    const int bh   = ((bid & 7) << 2) | (bid >> 7);
    const int qt   = (bid >> 3) & 15;
    const int l5   = lane & 31;
    const int hi   = lane >> 5;

    // staging lane geometry: row-within-8-group + inverse-swizzled chunk
    const int rsub = lane >> 3;                  // 0..7
    const int csw  = (lane & 7) ^ rsub;          // chunk this lane fetches
    // fragment-read swizzled chunk offsets (elements), per-lane constant
    int cc[4];
#pragma unroll
    for (int i = 0; i < 4; ++i) cc[i] = ((2 * i + hi) ^ (l5 & 7)) * 8;

    // Q B-frags (B[n=q][k=d]), q = qt*128 + w*32 + l5, held in regs
    const bf16_t* qrow = Qb + ((size_t)bh * S_LEN + qt * 128 + w * 32 + l5) * 64 + hi * 8;
    bf16x8 qf[4];
#pragma unroll
    for (int ds = 0; ds < 4; ++ds) qf[ds] = *(const bf16x8*)(qrow + ds * 16);

    f32x16 oacc[2];
#pragma unroll
    for (int dh = 0; dh < 2; ++dh)
#pragma unroll
        for (int i = 0; i < 16; ++i) oacc[dh][i] = 0.f;
    float plsum = 0.f;

    // coalesced staging: instr i covers rows 8i..8i+7, LDS bytes [1024i,1024i+1024)
    auto stageKV = [&](int kt, int buf) {
        bf16_t* ksb = &Ks[buf][0];
        bf16_t* vsb = &Vts[buf][0];
        const bf16_t* kg = Kb + ((size_t)bh * S_LEN + kt * 64) * 64;
        const bf16_t* vg = Vtb + (size_t)bh * 64 * S_LEN + kt * 64;
#pragma unroll
        for (int j = 0; j < 2; ++j) {
            int i = w * 2 + j;
            g2l16(kg + (size_t)(i * 8 + rsub) * 64 + csw * 8,    ksb + i * 512);
            g2l16(vg + (size_t)(i * 8 + rsub) * S_LEN + csw * 8, vsb + i * 512);
        }
    };

    stageKV(0, 0);
    for (int kt = 0; kt < 32; ++kt) {
        const int cur = kt & 1;
        asm volatile("s_waitcnt vmcnt(0)" ::: "memory");
        __syncthreads();
        if (kt < 31) stageKV(kt + 1, cur ^ 1);

        // ---- S^T = K·Q^T per key half (log2 domain) ----
        f32x16 sacc[2];
        __builtin_amdgcn_s_setprio(1);
#pragma unroll
        for (int kh = 0; kh < 2; ++kh) {
#pragma unroll
            for (int i = 0; i < 16; ++i) sacc[kh][i] = 0.f;
#pragma unroll
            for (int ds = 0; ds < 4; ++ds) {
                bf16x8 kf = *(const bf16x8*)&Ks[cur][(kh * 32 + l5) * 64 + cc[ds]];
                sacc[kh] = __builtin_amdgcn_mfma_f32_32x32x16_bf16(kf, qf[ds], sacc[kh], 0, 0, 0);
            }
        }
        __builtin_amdgcn_s_setprio(0);

        // ---- toroidal bias: only near-diagonal K-tiles ----
        int ktd = (kt - 2 * qt) & 31;
        if (ktd <= 2 || ktd == 31) {
            int q = qt * 128 + w * 32 + l5;
#pragma unroll
            for (int kh = 0; kh < 2; ++kh)
#pragma unroll
                for (int r = 0; r < 16; ++r) {
                    int key  = kt * 64 + kh * 32 + (r & 3) + 8 * (r >> 2) + 4 * hi;
                    int diff = (key - q) & (S_LEN - 1);
                    if (diff <= 1 || diff == S_LEN - 1) sacc[kh][r] += L2E;
                }
        }

        // ---- p = 2^S, all in registers ----
        float pv[2][16];
#pragma unroll
        for (int kh = 0; kh < 2; ++kh)
#pragma unroll
            for (int i = 0; i < 16; ++i) {
                pv[kh][i] = __builtin_amdgcn_exp2f(sacc[kh][i]);
                plsum += pv[kh][i];
            }

        // ---- PV A-frags: pure in-lane repack (V rows are bit-2/3-swapped) ----
        bf16x8 pf[4];
#pragma unroll
        for (int ks = 0; ks < 4; ++ks) {
            const int kh = ks >> 1, m = ks & 1;
#pragma unroll
            for (int e = 0; e < 8; ++e)
                pf[ks][e] = (bf16_t)pv[kh][(e & 3) + 8 * m + 4 * (e >> 2)];
        }

        // ---- PV: O[q][d] += P·V ----
        __builtin_amdgcn_s_setprio(1);
#pragma unroll
        for (int dh = 0; dh < 2; ++dh) {
#pragma unroll
            for (int ks = 0; ks < 4; ++ks) {
                bf16x8 vf = *(const bf16x8*)&Vts[cur][(dh * 32 + l5) * 64 + cc[ks]];
                oacc[dh] = __builtin_amdgcn_mfma_f32_32x32x16_bf16(pf[ks], vf, oacc[dh], 0, 0, 0);
            }
        }
        __builtin_amdgcn_s_setprio(0);
    }

    // ---- l: lane + lane^32 hold the two key-halves of row q=l5 ----
    plsum += __shfl_xor(plsum, 32, 64);
    if (hi == 0) Lw4[w][l5] = plsum;

    float inv16[16];
#pragma unroll
    for (int g = 0; g < 4; ++g) {
        f32x4 lv = *(const f32x4*)&Lw4[w][8 * g + 4 * hi];
#pragma unroll
        for (int e = 0; e < 4; ++e) inv16[g * 4 + e] = 1.0f / lv[e];
    }

    const int b = bh >> 4, h = bh & 15;
#pragma unroll
    for (int dh = 0; dh < 2; ++dh)
#pragma unroll
        for (int r = 0; r < 16; ++r) {
            int qrel = (r & 3) + 8 * (r >> 2) + 4 * hi;
            int s = qt * 128 + w * 32 + qrel;
            O[((size_t)(s * NB + b)) * EMB + h * 64 + dh * 32 + l5] =
                (bf16_t)(oacc[dh][r] * inv16[r]);
        }
}

// ---------------------------------------------------------------------------
// Workspace map (42 MB):
//   [ 0, 8) xb -> reused as Qb | [ 8,10) wtorb | [10,16) ipwb | [16,18) outwb
//   [18,26) xtb -> reused as Ob | [26,34) Kb | [34,42) Vtb (permuted cols)
// ---------------------------------------------------------------------------
extern "C" void kernel_launch(void* const* d_in, const int* in_sizes, int n_in,
                              void* d_out, int out_size, void* d_ws, size_t ws_size,
                              hipStream_t stream)
{
    const float* x         = (const float*)d_in[0];
    const float* w_tor     = (const float*)d_in[1];
    const float* b_tor     = (const float*)d_in[2];
    const float* in_proj_w = (const float*)d_in[3];
    const float* in_proj_b = (const float*)d_in[4];
    const float* out_w     = (const float*)d_in[5];
    const float* out_b     = (const float*)d_in[6];
    float* out = (float*)d_out;

    const int M = S_LEN * NB;   // 4096

    char* base = (char*)d_ws;
    bf16_t* xb    = (bf16_t*)(base);
    bf16_t* wtorb = (bf16_t*)(base + ( 8ull << 20));
    bf16_t* ipwb  = (bf16_t*)(base + (10ull << 20));
    bf16_t* outwb = (bf16_t*)(base + (16ull << 20));
    bf16_t* xtb   = (bf16_t*)(base + (18ull << 20));
    bf16_t* Kb    = (bf16_t*)(base + (26ull << 20));
    bf16_t* Vtb   = (bf16_t*)(base + (34ull << 20));
    bf16_t* Qb    = xb;    // alias: xb dead once GEMM1 has run
    bf16_t* Ob    = xtb;   // alias: xtb dead once GEMM2 has run

    cast4_f32_bf16<<<dim3(9216), 256, 0, stream>>>(
        x, xb, w_tor, wtorb, in_proj_w, ipwb, out_w, outwb);

    // GEMM1: 32 m-tiles x 16 n-tiles = 512 blocks (1D, XCD-rect swizzled)
    gemm_bt_bf16<64, 1, 32, 16><<<dim3(512), 256, 0, stream>>>(
        xb, wtorb, b_tor, xtb, nullptr, nullptr, nullptr, M, EMB, EMB);

    // GEMM2: 32 m-tiles x 24 n-tiles = 768 blocks
    gemm_bt_bf16<128, 2, 32, 24><<<dim3(768), 256, 0, stream>>>(
        xtb, ipwb, in_proj_b, nullptr, Qb, Kb, Vtb, M, 3 * EMB, EMB);

    attn_mfma<<<dim3(32 * 16), 256, 0, stream>>>(Qb, Kb, Vtb, Ob);

    // GEMM3: 32 x 16 = 512 blocks
    gemm_bt_bf16<64, 0, 32, 16><<<dim3(512), 256, 0, stream>>>(
        Ob, outwb, out_b, out, nullptr, nullptr, nullptr, M, EMB, EMB);
}

// Round 11
// 196.791 us; speedup vs baseline: 1.1627x; 1.0610x over previous
//
#include <hip/hip_runtime.h>

#define S_LEN 2048
#define NB    2
#define EMB   1024
#define NH    16
#define HD    64

typedef __bf16 bf16_t;
typedef bf16_t bf16x8 __attribute__((ext_vector_type(8)));
typedef bf16_t bf16x4v __attribute__((ext_vector_type(4)));
typedef float  f32x4  __attribute__((ext_vector_type(4)));
typedef float  f32x16 __attribute__((ext_vector_type(16)));

#define L2E 1.44269504f   // log2(e)

// async global->LDS, 16B per lane; LDS dest = wave-uniform base + lane*16
__device__ __forceinline__ void g2l16(const void* g, void* l) {
    auto gp = reinterpret_cast<const unsigned int __attribute__((address_space(1)))*>(
        reinterpret_cast<uintptr_t>(g));
    auto lp = reinterpret_cast<unsigned int __attribute__((address_space(3)))*>(
        reinterpret_cast<uintptr_t>(l));
    __builtin_amdgcn_global_load_lds(gp, lp, 16, 0, 0);
}

// pack two f32 -> one u32 of 2 bf16 (h[0] = a = low address on store)
__device__ __forceinline__ unsigned int pk2(float a, float b) {
    union { unsigned int u; bf16_t h[2]; } r;
    r.h[0] = (bf16_t)a; r.h[1] = (bf16_t)b;
    return r.u;
}

// ---------------------------------------------------------------------------
// Fused fp32 -> bf16 cast of x, w_tor, in_proj_w, out_w (float4 granularity).
// ---------------------------------------------------------------------------
__global__ __launch_bounds__(256) void cast4_f32_bf16(
    const float* __restrict__ s0, bf16_t* __restrict__ d0,
    const float* __restrict__ s1, bf16_t* __restrict__ d1,
    const float* __restrict__ s2, bf16_t* __restrict__ d2,
    const float* __restrict__ s3, bf16_t* __restrict__ d3)
{
    long i = (long)blockIdx.x * 256 + threadIdx.x;
    const float* s; bf16_t* d; long off;
    if (i < 1048576)      { s = s0; d = d0; off = i; }
    else if (i < 1310720) { s = s1; d = d1; off = i - 1048576; }
    else if (i < 2097152) { s = s2; d = d2; off = i - 1310720; }
    else                  { s = s3; d = d3; off = i - 2097152; }
    float4 v = ((const float4*)s)[off];
    bf16x4v o;
    o[0] = (bf16_t)v.x; o[1] = (bf16_t)v.y; o[2] = (bf16_t)v.z; o[3] = (bf16_t)v.w;
    *(bf16x4v*)(d + off * 4) = o;
}

// ---------------------------------------------------------------------------
// bf16 MFMA GEMM, double-buffered prefetch K-loop, BK=64 (R11):
//   each staged buffer holds TWO 32-K sub-tiles (kh=0,1) computed
//   sequentially -> barriers per block halve (32 -> 16) while accumulation
//   order stays bit-identical to BK=32. MFMA per barrier-pair: 16 -> 32
//   (TN=64/128) or 48 (TN=192).
// C(M,N) = A(M,K) @ W(N,K)^T + bias(N). TM=128, TN in {64,128,192}.
// MODE: 0 = fp32 out, 1 = bf16 out, 2 = qkv head-layout epilogue:
//   Q pre-scaled by 0.125*log2e; K natural [b,h,s,d]; V transposed [b,h,d,s]
//   with KEY-SLOT PERMUTATION (swap bits 2<->3 of s): makes the attn PV
//   A-fragment equal an in-lane repack of the QK^T output (P stays in regs).
// R9/R10: bijective 2D-rect XCD swizzle kept (null measured, harmless).
// Dynamic LDS: 32KB (A) + TN*256 B bytes; TN=192 -> 80KB (needs attribute).
// Pinned: R6 grid 192 on 256 CUs (25% idle) regressed; all grids here are
// exact multiples of 256 (2/CU, no tail).
// ---------------------------------------------------------------------------
template<int TN, int MODE, int MT, int NT>
__global__ __launch_bounds__(256, 2) void gemm_bt_bf16(
    const bf16_t* __restrict__ A, const bf16_t* __restrict__ W,
    const float* __restrict__ bias, void* __restrict__ Cout,
    bf16_t* __restrict__ Qp, bf16_t* __restrict__ Kp, bf16_t* __restrict__ Vtp,
    int M, int N, int K)
{
    constexpr int MB  = (TN == 64) ? 2 : 4;
    constexpr int NBn = (TN == 64) ? 4 : TN / 32;
    constexpr int BI  = TN / 64;              // B staging instrs/wave/kh
    extern __shared__ __align__(16) char smem[];
    bf16_t* AsB = (bf16_t*)smem;                    // [2][2][128*32]
    bf16_t* BsB = (bf16_t*)(smem + 32768);          // [2][2][TN*32]

    const int tid  = threadIdx.x;
    const int lane = tid & 63;
    const int w    = tid >> 6;
    const int lm   = lane & 15;
    const int lq   = lane >> 4;

    // 2D-rect XCD swizzle: 4 m-rects x 2 n-rects = 8 XCDs
    constexpr int MR = MT / 4;
    constexpr int NR = NT / 2;
    const int bid  = blockIdx.x;
    const int xcd  = bid & 7;
    const int idx  = bid >> 3;                 // [0, MR*NR)
    const long m0  = (long)((xcd >> 1) * MR + idx / NR) * 128;
    const long n0  = (long)((xcd & 1) * NR + idx % NR) * TN;

    const int wm0  = (TN == 64) ? w * 32 : (w >> 1) * 64;
    const int wn0  = (TN == 64) ? 0 : (w & 1) * (TN / 2);

    f32x4 acc[MB][NBn];
#pragma unroll
    for (int i = 0; i < MB; ++i)
#pragma unroll
        for (int j = 0; j < NBn; ++j) acc[i][j] = (f32x4){0.f, 0.f, 0.f, 0.f};

    auto stage = [&](int t, int buf) {
        const int k0 = t * 64;
        bf16_t* asb = AsB + buf * 8192;
#pragma unroll
        for (int j = 0; j < 4; ++j) {
            int kh = j >> 1, jj = j & 1;
            int a   = (w * 2 + jj) * 64 + lane;
            int row = a >> 2;
            int c   = (a & 3) ^ ((row >> 1) & 3);
            g2l16(A + (m0 + row) * K + k0 + kh * 32 + c * 8,
                  asb + kh * 4096 + (w * 2 + jj) * 512);
        }
        bf16_t* bsb = BsB + buf * (TN * 64);
#pragma unroll
        for (int j = 0; j < 2 * BI; ++j) {
            int kh = j / BI, jj = j % BI;
            int a   = (w * BI + jj) * 64 + lane;
            int row = a >> 2;
            int c   = (a & 3) ^ ((row >> 1) & 3);
            g2l16(W + (n0 + row) * K + k0 + kh * 32 + c * 8,
                  bsb + kh * (TN * 32) + (w * BI + jj) * 512);
        }
    };

    stage(0, 0);
    const int NTILES = K / 64;
    for (int t = 0; t < NTILES; ++t) {
        const int cur = t & 1;
        asm volatile("s_waitcnt vmcnt(0)" ::: "memory");
        __syncthreads();
        if (t + 1 < NTILES) stage(t + 1, cur ^ 1);

#pragma unroll
        for (int kh = 0; kh < 2; ++kh) {
            const bf16_t* Ab = AsB + cur * 8192 + kh * 4096;
            const bf16_t* Bb = BsB + cur * (TN * 64) + kh * (TN * 32);
            bf16x8 af[MB], bfr[NBn];
#pragma unroll
            for (int mb = 0; mb < MB; ++mb) {
                int r = wm0 + mb * 16 + lm;
                af[mb] = *(const bf16x8*)&Ab[r * 32 + ((lq ^ ((r >> 1) & 3)) << 3)];
            }
#pragma unroll
            for (int nb = 0; nb < NBn; ++nb) {
                int r = wn0 + nb * 16 + lm;
                bfr[nb] = *(const bf16x8*)&Bb[r * 32 + ((lq ^ ((r >> 1) & 3)) << 3)];
            }
#pragma unroll
            for (int mb = 0; mb < MB; ++mb)
#pragma unroll
                for (int nb = 0; nb < NBn; ++nb)
                    acc[mb][nb] = __builtin_amdgcn_mfma_f32_16x16x32_bf16(
                        af[mb], bfr[nb], acc[mb][nb], 0, 0, 0);
        }
    }

    // ---- epilogue ----
    float b4[NBn];
#pragma unroll
    for (int nb = 0; nb < NBn; ++nb) b4[nb] = bias[n0 + wn0 + nb * 16 + lm];

    if (MODE == 2) {
#pragma unroll
        for (int mb = 0; mb < MB; ++mb) {
            const long mbase = m0 + wm0 + mb * 16 + lq * 4;   // even
#pragma unroll
            for (int nb = 0; nb < NBn; ++nb) {
                int n    = (int)n0 + wn0 + nb * 16 + lm;
                int sec  = n >> 10;
                int nloc = n & 1023;
                int h    = nloc >> 6;
                int d    = nloc & 63;
                if (sec == 2) {
                    // paired Vt store at PERMUTED slot: swap bits 2<->3 of s
                    int s0 = (int)(mbase >> 1);
                    int sp = (s0 & ~12) | ((s0 & 4) << 1) | ((s0 & 8) >> 1);
#pragma unroll
                    for (int rp = 0; rp < 2; ++rp) {
                        int bh = rp * 16 + h;
                        unsigned int pkv = pk2(acc[mb][nb][rp]     + b4[nb],
                                               acc[mb][nb][rp + 2] + b4[nb]);
                        *(unsigned int*)&Vtp[((size_t)(bh * 64 + d)) * S_LEN + sp] = pkv;
                    }
                } else {
#pragma unroll
                    for (int r = 0; r < 4; ++r) {
                        long m  = mbase + r;
                        int  s  = (int)(m >> 1), b = (int)(m & 1);
                        int  bh = b * 16 + h;
                        float v = acc[mb][nb][r] + b4[nb];
                        if (sec == 0) {
                            Qp[((size_t)(bh * S_LEN + s)) * 64 + d] =
                                (bf16_t)(v * (0.125f * L2E));
                        } else {
                            Kp[((size_t)(bh * S_LEN + s)) * 64 + d] = (bf16_t)v;
                        }
                    }
                }
            }
        }
    } else {
#pragma unroll
        for (int mb = 0; mb < MB; ++mb) {
#pragma unroll
            for (int r = 0; r < 4; ++r) {
                long m = m0 + wm0 + mb * 16 + lq * 4 + r;
#pragma unroll
                for (int nb = 0; nb < NBn; ++nb) {
                    int n   = (int)n0 + wn0 + nb * 16 + lm;
                    float v = acc[mb][nb][r] + b4[nb];
                    if (MODE == 0) ((float*)Cout)[m * N + n] = v;
                    else           ((bf16_t*)Cout)[m * N + n] = (bf16_t)v;
                }
            }
        }
    }
}

// ---------------------------------------------------------------------------
// MFMA flash attention — R7 configuration VERBATIM (measured 50.4-51.1us,
// best of R0..R10): R3 skeleton (256 thr / 4 waves / 32 iters / 2 blocks/CU,
// coalesced staging + XOR slot(row,c)=row*8+(c^(row&7)) K/V layout, XCD bh
// swizzle, setprio) + in-register P via V key-row bit-2/3 swap.
// Pinned lessons: R1 permlane-P slower (serial VALU); R2 key-split slower;
// R4 64q/wave (1 wave/SIMD) much slower; R8 V-bypass-LDS much slower (direct
// V reg loads = 32 lines/instr uncoalesced gather); 2 blocks/CU minimum.
// ---------------------------------------------------------------------------
__global__ __launch_bounds__(256, 2) void attn_mfma(
    const bf16_t* __restrict__ Qb, const bf16_t* __restrict__ Kb,
    const bf16_t* __restrict__ Vtb, bf16_t* __restrict__ O)
{
    __shared__ __align__(16) bf16_t Ks[2][8 * 512];    // 16 KB, swizzled rows
    __shared__ __align__(16) bf16_t Vts[2][8 * 512];   // 16 KB, swizzled rows
    __shared__ __align__(16) float  Lw4[4][32];        // per-wave row sums

    const int tid  = threadIdx.x;
    const int lane = tid & 63;
    const int w    = tid >> 6;
    const int bid  = blockIdx.x;
    // XCD swizzle: XCD x gets blocks {x, x+8, ...} = 4 consecutive bh
    const int bh   = ((bid & 7) << 2) | (bid >> 7);
    const int qt   = (bid >> 3) & 15;
    const int l5   = lane & 31;
    const int hi   = lane >> 5;

    // staging lane geometry: row-within-8-group + inverse-swizzled chunk
    const int rsub = lane >> 3;                  // 0..7
    const int csw  = (lane & 7) ^ rsub;          // chunk this lane fetches
    // fragment-read swizzled chunk offsets (elements), per-lane constant
    int cc[4];
#pragma unroll
    for (int i = 0; i < 4; ++i) cc[i] = ((2 * i + hi) ^ (l5 & 7)) * 8;

    // Q B-frags (B[n=q][k=d]), q = qt*128 + w*32 + l5, held in regs
    const bf16_t* qrow = Qb + ((size_t)bh * S_LEN + qt * 128 + w * 32 + l5) * 64 + hi * 8;
    bf16x8 qf[4];
#pragma unroll
    for (int ds = 0; ds < 4; ++ds) qf[ds] = *(const bf16x8*)(qrow + ds * 16);

    f32x16 oacc[2];
#pragma unroll
    for (int dh = 0; dh < 2; ++dh)
#pragma unroll
        for (int i = 0; i < 16; ++i) oacc[dh][i] = 0.f;
    float plsum = 0.f;

    // coalesced staging: instr i covers rows 8i..8i+7, LDS bytes [1024i,1024i+1024)
    auto stageKV = [&](int kt, int buf) {
        bf16_t* ksb = &Ks[buf][0];
        bf16_t* vsb = &Vts[buf][0];
        const bf16_t* kg = Kb + ((size_t)bh * S_LEN + kt * 64) * 64;
        const bf16_t* vg = Vtb + (size_t)bh * 64 * S_LEN + kt * 64;
#pragma unroll
        for (int j = 0; j < 2; ++j) {
            int i = w * 2 + j;
            g2l16(kg + (size_t)(i * 8 + rsub) * 64 + csw * 8,    ksb + i * 512);
            g2l16(vg + (size_t)(i * 8 + rsub) * S_LEN + csw * 8, vsb + i * 512);
        }
    };

    stageKV(0, 0);
    for (int kt = 0; kt < 32; ++kt) {
        const int cur = kt & 1;
        asm volatile("s_waitcnt vmcnt(0)" ::: "memory");
        __syncthreads();
        if (kt < 31) stageKV(kt + 1, cur ^ 1);

        // ---- S^T = K·Q^T per key half (log2 domain) ----
        f32x16 sacc[2];
        __builtin_amdgcn_s_setprio(1);
#pragma unroll
        for (int kh = 0; kh < 2; ++kh) {
#pragma unroll
            for (int i = 0; i < 16; ++i) sacc[kh][i] = 0.f;
#pragma unroll
            for (int ds = 0; ds < 4; ++ds) {
                bf16x8 kf = *(const bf16x8*)&Ks[cur][(kh * 32 + l5) * 64 + cc[ds]];
                sacc[kh] = __builtin_amdgcn_mfma_f32_32x32x16_bf16(kf, qf[ds], sacc[kh], 0, 0, 0);
            }
        }
        __builtin_amdgcn_s_setprio(0);

        // ---- toroidal bias: only near-diagonal K-tiles ----
        int ktd = (kt - 2 * qt) & 31;
        if (ktd <= 2 || ktd == 31) {
            int q = qt * 128 + w * 32 + l5;
#pragma unroll
            for (int kh = 0; kh < 2; ++kh)
#pragma unroll
                for (int r = 0; r < 16; ++r) {
                    int key  = kt * 64 + kh * 32 + (r & 3) + 8 * (r >> 2) + 4 * hi;
                    int diff = (key - q) & (S_LEN - 1);
                    if (diff <= 1 || diff == S_LEN - 1) sacc[kh][r] += L2E;
                }
        }

        // ---- p = 2^S, all in registers ----
        float pv[2][16];
#pragma unroll
        for (int kh = 0; kh < 2; ++kh)
#pragma unroll
            for (int i = 0; i < 16; ++i) {
                pv[kh][i] = __builtin_amdgcn_exp2f(sacc[kh][i]);
                plsum += pv[kh][i];
            }

        // ---- PV A-frags: pure in-lane repack (V rows are bit-2/3-swapped) ----
        bf16x8 pf[4];
#pragma unroll
        for (int ks = 0; ks < 4; ++ks) {
            const int kh = ks >> 1, m = ks & 1;
#pragma unroll
            for (int e = 0; e < 8; ++e)
                pf[ks][e] = (bf16_t)pv[kh][(e & 3) + 8 * m + 4 * (e >> 2)];
        }

        // ---- PV: O[q][d] += P·V ----
        __builtin_amdgcn_s_setprio(1);
#pragma unroll
        for (int dh = 0; dh < 2; ++dh) {
#pragma unroll
            for (int ks = 0; ks < 4; ++ks) {
                bf16x8 vf = *(const bf16x8*)&Vts[cur][(dh * 32 + l5) * 64 + cc[ks]];
                oacc[dh] = __builtin_amdgcn_mfma_f32_32x32x16_bf16(pf[ks], vf, oacc[dh], 0, 0, 0);
            }
        }
        __builtin_amdgcn_s_setprio(0);
    }

    // ---- l: lane + lane^32 hold the two key-halves of row q=l5 ----
    plsum += __shfl_xor(plsum, 32, 64);
    if (hi == 0) Lw4[w][l5] = plsum;

    float inv16[16];
#pragma unroll
    for (int g = 0; g < 4; ++g) {
        f32x4 lv = *(const f32x4*)&Lw4[w][8 * g + 4 * hi];
#pragma unroll
        for (int e = 0; e < 4; ++e) inv16[g * 4 + e] = 1.0f / lv[e];
    }

    const int b = bh >> 4, h = bh & 15;
#pragma unroll
    for (int dh = 0; dh < 2; ++dh)
#pragma unroll
        for (int r = 0; r < 16; ++r) {
            int qrel = (r & 3) + 8 * (r >> 2) + 4 * hi;
            int s = qt * 128 + w * 32 + qrel;
            O[((size_t)(s * NB + b)) * EMB + h * 64 + dh * 32 + l5] =
                (bf16_t)(oacc[dh][r] * inv16[r]);
        }
}

// ---------------------------------------------------------------------------
// Workspace map (42 MB):
//   [ 0, 8) xb -> reused as Qb | [ 8,10) wtorb | [10,16) ipwb | [16,18) outwb
//   [18,26) xtb -> reused as Ob | [26,34) Kb | [34,42) Vtb (permuted cols)
// ---------------------------------------------------------------------------
extern "C" void kernel_launch(void* const* d_in, const int* in_sizes, int n_in,
                              void* d_out, int out_size, void* d_ws, size_t ws_size,
                              hipStream_t stream)
{
    const float* x         = (const float*)d_in[0];
    const float* w_tor     = (const float*)d_in[1];
    const float* b_tor     = (const float*)d_in[2];
    const float* in_proj_w = (const float*)d_in[3];
    const float* in_proj_b = (const float*)d_in[4];
    const float* out_w     = (const float*)d_in[5];
    const float* out_b     = (const float*)d_in[6];
    float* out = (float*)d_out;

    const int M = S_LEN * NB;   // 4096

    char* base = (char*)d_ws;
    bf16_t* xb    = (bf16_t*)(base);
    bf16_t* wtorb = (bf16_t*)(base + ( 8ull << 20));
    bf16_t* ipwb  = (bf16_t*)(base + (10ull << 20));
    bf16_t* outwb = (bf16_t*)(base + (16ull << 20));
    bf16_t* xtb   = (bf16_t*)(base + (18ull << 20));
    bf16_t* Kb    = (bf16_t*)(base + (26ull << 20));
    bf16_t* Vtb   = (bf16_t*)(base + (34ull << 20));
    bf16_t* Qb    = xb;    // alias: xb dead once GEMM1 has run
    bf16_t* Ob    = xtb;   // alias: xtb dead once GEMM2 has run

    // dynamic LDS sizes: 32KB (A dbuf) + TN*256 bytes (B dbuf)
    const int lds64  = 32768 + 64 * 256;    // 48 KB (G1/G3)
    const int lds192 = 32768 + 192 * 256;   // 80 KB (G2) -> needs attribute
    hipFuncSetAttribute((const void*)gemm_bt_bf16<192, 2, 32, 16>,
                        hipFuncAttributeMaxDynamicSharedMemorySize, lds192);

    cast4_f32_bf16<<<dim3(9216), 256, 0, stream>>>(
        x, xb, w_tor, wtorb, in_proj_w, ipwb, out_w, outwb);

    // GEMM1: 32 m-tiles x 16 n-tiles = 512 blocks (2/CU exact), BK=64
    gemm_bt_bf16<64, 1, 32, 16><<<dim3(512), 256, lds64, stream>>>(
        xb, wtorb, b_tor, xtb, nullptr, nullptr, nullptr, M, EMB, EMB);

    // GEMM2: TN=192 -> 32 x 16 = 512 blocks (2/CU exact, no tail), BK=64
    gemm_bt_bf16<192, 2, 32, 16><<<dim3(512), 256, lds192, stream>>>(
        xtb, ipwb, in_proj_b, nullptr, Qb, Kb, Vtb, M, 3 * EMB, EMB);

    attn_mfma<<<dim3(32 * 16), 256, 0, stream>>>(Qb, Kb, Vtb, Ob);

    // GEMM3: 32 x 16 = 512 blocks, BK=64
    gemm_bt_bf16<64, 0, 32, 16><<<dim3(512), 256, lds64, stream>>>(
        Ob, outwb, out_b, out, nullptr, nullptr, nullptr, M, EMB, EMB);
}